// Round 3
// baseline (473.069 us; speedup 1.0000x reference)
//
#include <hip/hip_runtime.h>

// GCN: out = relu(segment_sum(feat[src], dst) @ W.T + b)
// feat: [N,64] f32, W: [64,64] f32, b: [64] f32, src/dst: [E] i32
// Strategy round 0/1/2: correctness-first baseline (rounds 1-2 = resubmit after infra timeouts).
//   K1: scatter-add, 64 threads/edge (lane=feature), atomicAdd f32.
//   K2: linear+relu, W^T staged in LDS (pad 65), 4 rows/block iter, in-place safe.

__global__ void gcn_scatter_kernel(const float* __restrict__ feat,
                                   const int* __restrict__ src,
                                   const int* __restrict__ dst,
                                   float* __restrict__ agg,
                                   int n_edges) {
    long long tid = (long long)blockIdx.x * blockDim.x + threadIdx.x;
    int e = (int)(tid >> 6);
    int f = (int)(tid & 63);
    if (e >= n_edges) return;
    int s = src[e];          // wave-uniform within quarter-wave -> scalarized
    int d = dst[e];
    float v = feat[(long long)s * 64 + f];
    atomicAdd(&agg[(long long)d * 64 + f], v);
}

__global__ void gcn_linear_relu_kernel(const float* __restrict__ agg,
                                       const float* __restrict__ W,
                                       const float* __restrict__ b,
                                       float* __restrict__ out,
                                       int n_nodes) {
    __shared__ float Wt[64 * 65];   // Wt[k*65+j] = W[j*64+k], padded -> conflict-free
    __shared__ float bs[64];
    __shared__ float rows[4 * 64];

    int tid = threadIdx.x;
    #pragma unroll
    for (int it = 0; it < 16; ++it) {
        int idx = it * 256 + tid;
        int j = idx >> 6;   // W row (output feature)
        int k = idx & 63;   // W col (input feature)
        Wt[k * 65 + j] = W[idx];
    }
    if (tid < 64) bs[tid] = b[tid];
    __syncthreads();

    int li = tid >> 6;      // local row 0..3
    int j  = tid & 63;      // output feature

    for (int r0 = blockIdx.x * 4; r0 < n_nodes; r0 += gridDim.x * 4) {
        int n = r0 + li;
        __syncthreads();                       // protect rows[] from previous iter
        if (n < n_nodes) rows[tid] = agg[(long long)n * 64 + j];
        __syncthreads();
        if (n < n_nodes) {
            float sum = bs[j];
            #pragma unroll
            for (int k = 0; k < 64; ++k)
                sum += rows[li * 64 + k] * Wt[k * 65 + j];
            out[(long long)n * 64 + j] = fmaxf(sum, 0.0f);
        }
    }
}

extern "C" void kernel_launch(void* const* d_in, const int* in_sizes, int n_in,
                              void* d_out, int out_size, void* d_ws, size_t ws_size,
                              hipStream_t stream) {
    const float* feat = (const float*)d_in[0];
    const float* W    = (const float*)d_in[1];
    const float* b    = (const float*)d_in[2];
    const int*   src  = (const int*)d_in[3];
    const int*   dst  = (const int*)d_in[4];
    float* out = (float*)d_out;

    int n_nodes = in_sizes[0] / 64;
    int n_edges = in_sizes[3];

    size_t agg_bytes = (size_t)n_nodes * 64 * sizeof(float);
    float* agg = (ws_size >= agg_bytes) ? (float*)d_ws : out;

    hipMemsetAsync(agg, 0, agg_bytes, stream);

    long long total = (long long)n_edges * 64;
    int blocks = (int)((total + 255) / 256);
    gcn_scatter_kernel<<<blocks, 256, 0, stream>>>(feat, src, dst, agg, n_edges);

    gcn_linear_relu_kernel<<<1280, 256, 0, stream>>>(agg, W, b, out, n_nodes);
}

// Round 6
// 430.460 us; speedup vs baseline: 1.0990x; 1.0990x over previous
//
#include <hip/hip_runtime.h>

// GCN: out = relu(segment_sum(feat[src], dst) @ W.T + b)
// Round 3/4/5: replace global f32 atomics (400 MB HBM write-through, 350us) with
// CSR build (counting sort by dst) + fused gather+linear kernel (no agg buffer).
// (Rounds 4-5 = resubmits after infra timeouts; round-3 kernel never measured.)
//   K0 memset deg; K1 histogram(dst); K2a/b/c exclusive scan -> indptr,cursor;
//   K3 fill sorted_src; K4 wave-per-node gather + in-register linear (W rows in
//   VGPRs, row broadcast via readlane) + relu -> out.
// Fallback to round-0 atomic path if ws_size too small.

#if __has_builtin(__builtin_amdgcn_readlane)
__device__ __forceinline__ float bcast_lane(float x, int k) {
    return __uint_as_float(__builtin_amdgcn_readlane(__float_as_uint(x), k));
}
#else
__device__ __forceinline__ float bcast_lane(float x, int k) {
    return __shfl(x, k, 64);
}
#endif

// ---------------- CSR build ----------------

__global__ void k_hist(const int* __restrict__ dst, int* __restrict__ deg, int E) {
    int e = blockIdx.x * blockDim.x + threadIdx.x;
    if (e < E) atomicAdd(&deg[dst[e]], 1);
}

// exclusive scan, 1024 elems/block
__global__ void k_scan_partial(const int* __restrict__ deg, int* __restrict__ indptr,
                               int* __restrict__ bsums, int N) {
    __shared__ int tmp[1024];
    int tid = threadIdx.x;
    int gid = blockIdx.x * 1024 + tid;
    int v = (gid < N) ? deg[gid] : 0;
    tmp[tid] = v;
    __syncthreads();
    for (int off = 1; off < 1024; off <<= 1) {
        int t = (tid >= off) ? tmp[tid - off] : 0;
        __syncthreads();
        tmp[tid] += t;
        __syncthreads();
    }
    if (gid < N) indptr[gid] = tmp[tid] - v;   // exclusive
    if (tid == 1023) bsums[blockIdx.x] = tmp[tid];
}

__global__ void k_scan_bsums(int* __restrict__ bsums, int nb) {
    __shared__ int tmp[256];
    int tid = threadIdx.x;
    int v = (tid < nb) ? bsums[tid] : 0;
    tmp[tid] = v;
    __syncthreads();
    for (int off = 1; off < 256; off <<= 1) {
        int t = (tid >= off) ? tmp[tid - off] : 0;
        __syncthreads();
        tmp[tid] += t;
        __syncthreads();
    }
    if (tid < nb) bsums[tid] = tmp[tid] - v;   // exclusive
}

__global__ void k_scan_add(int* __restrict__ indptr, int* __restrict__ cursor,
                           const int* __restrict__ bsums, int N) {
    int i = blockIdx.x * blockDim.x + threadIdx.x;
    if (i < N) {
        int v = indptr[i] + bsums[i >> 10];
        indptr[i] = v;
        cursor[i] = v;
    }
}

__global__ void k_fill(const int* __restrict__ src, const int* __restrict__ dst,
                       int* __restrict__ cursor, int* __restrict__ sorted_src, int E) {
    int e = blockIdx.x * blockDim.x + threadIdx.x;
    if (e < E) {
        int p = atomicAdd(&cursor[dst[e]], 1);
        sorted_src[p] = src[e];
    }
}

// ---------------- fused gather + linear + relu ----------------
// wave per node (lane = feature). After the gather, lane f holds agg[n][f];
// linear done in-register: lane j keeps W row j (64 f32 in VGPRs), row values
// broadcast across the wave with readlane. cursor[n] holds row end after fill.

__global__ void k_gather_linear(const float* __restrict__ feat,
                                const float* __restrict__ W,
                                const float* __restrict__ b,
                                const int* __restrict__ indptr,
                                const int* __restrict__ cursor,
                                const int* __restrict__ sorted_src,
                                float* __restrict__ out, int N) {
    int lane = threadIdx.x & 63;
    int wid = (blockIdx.x * blockDim.x + threadIdx.x) >> 6;
    int nw = (gridDim.x * blockDim.x) >> 6;

    // W row 'lane' into registers (row-major [j][k], j = lane)
    float4 w[16];
    const float4* Wv = (const float4*)(W + lane * 64);
    #pragma unroll
    for (int q = 0; q < 16; ++q) w[q] = Wv[q];
    float bj = b[lane];

    for (int n = wid; n < N; n += nw) {
        int beg = indptr[n];
        int end = cursor[n];
        float sum = 0.0f;
        int i = beg;
        for (; i + 1 < end; i += 2) {
            int s0 = sorted_src[i];
            int s1 = sorted_src[i + 1];
            float v0 = feat[s0 * 64 + lane];
            float v1 = feat[s1 * 64 + lane];
            sum += v0 + v1;
        }
        if (i < end) sum += feat[sorted_src[i] * 64 + lane];

        float acc = bj;
        #pragma unroll
        for (int k = 0; k < 64; ++k) {
            float rk = bcast_lane(sum, k);
            acc = fmaf(rk, ((const float*)w)[k], acc);
        }
        out[n * 64 + lane] = fmaxf(acc, 0.0f);
    }
}

// ---------------- fallback: round-0 atomic path ----------------

__global__ void gcn_scatter_kernel(const float* __restrict__ feat,
                                   const int* __restrict__ src,
                                   const int* __restrict__ dst,
                                   float* __restrict__ agg,
                                   int n_edges) {
    long long tid = (long long)blockIdx.x * blockDim.x + threadIdx.x;
    int e = (int)(tid >> 6);
    int f = (int)(tid & 63);
    if (e >= n_edges) return;
    int s = src[e];
    int d = dst[e];
    atomicAdd(&agg[(long long)d * 64 + f], feat[(long long)s * 64 + f]);
}

__global__ void gcn_linear_relu_kernel(const float* __restrict__ agg,
                                       const float* __restrict__ W,
                                       const float* __restrict__ b,
                                       float* __restrict__ out,
                                       int n_nodes) {
    __shared__ float Wt[64 * 65];
    __shared__ float bs[64];
    __shared__ float rows[4 * 64];
    int tid = threadIdx.x;
    #pragma unroll
    for (int it = 0; it < 16; ++it) {
        int idx = it * 256 + tid;
        Wt[(idx & 63) * 65 + (idx >> 6)] = W[idx];
    }
    if (tid < 64) bs[tid] = b[tid];
    __syncthreads();
    int li = tid >> 6, j = tid & 63;
    for (int r0 = blockIdx.x * 4; r0 < n_nodes; r0 += gridDim.x * 4) {
        int n = r0 + li;
        __syncthreads();
        if (n < n_nodes) rows[tid] = agg[(long long)n * 64 + j];
        __syncthreads();
        if (n < n_nodes) {
            float sum = bs[j];
            #pragma unroll
            for (int k = 0; k < 64; ++k)
                sum += rows[li * 64 + k] * Wt[k * 65 + j];
            out[(long long)n * 64 + j] = fmaxf(sum, 0.0f);
        }
    }
}

extern "C" void kernel_launch(void* const* d_in, const int* in_sizes, int n_in,
                              void* d_out, int out_size, void* d_ws, size_t ws_size,
                              hipStream_t stream) {
    const float* feat = (const float*)d_in[0];
    const float* W    = (const float*)d_in[1];
    const float* b    = (const float*)d_in[2];
    const int*   src  = (const int*)d_in[3];
    const int*   dst  = (const int*)d_in[4];
    float* out = (float*)d_out;

    int N = in_sizes[0] / 64;
    int E = in_sizes[3];

    // ws layout: deg[N] | indptr[N] | cursor[N] | bsums[256] | sorted_src[E]
    size_t need = ((size_t)3 * N + 256 + (size_t)E) * sizeof(int);

    if (ws_size >= need) {
        int* deg        = (int*)d_ws;
        int* indptr     = deg + N;
        int* cursor     = indptr + N;
        int* bsums      = cursor + N;
        int* sorted_src = bsums + 256;

        hipMemsetAsync(deg, 0, (size_t)N * sizeof(int), stream);

        int tb = 256;
        k_hist<<<(E + tb - 1) / tb, tb, 0, stream>>>(dst, deg, E);

        int nb = (N + 1023) / 1024;   // 98 for N=100000 (<=256 supported)
        k_scan_partial<<<nb, 1024, 0, stream>>>(deg, indptr, bsums, N);
        k_scan_bsums<<<1, 256, 0, stream>>>(bsums, nb);
        k_scan_add<<<(N + tb - 1) / tb, tb, 0, stream>>>(indptr, cursor, bsums, N);

        k_fill<<<(E + tb - 1) / tb, tb, 0, stream>>>(src, dst, cursor, sorted_src, E);

        k_gather_linear<<<2048, 256, 0, stream>>>(feat, W, b, indptr, cursor,
                                                  sorted_src, out, N);
    } else {
        // fallback: atomic scatter into out (in-place-safe linear)
        float* agg = out;
        hipMemsetAsync(agg, 0, (size_t)N * 64 * sizeof(float), stream);
        long long total = (long long)E * 64;
        gcn_scatter_kernel<<<(int)((total + 255) / 256), 256, 0, stream>>>(feat, src, dst, agg, E);
        gcn_linear_relu_kernel<<<1280, 256, 0, stream>>>(agg, W, b, out, N);
    }
}

// Round 8
// 334.810 us; speedup vs baseline: 1.4129x; 1.2857x over previous
//
#include <hip/hip_runtime.h>

// GCN: out = relu(segment_sum(feat[src], dst) @ W.T + b)
// Round 7 (resubmit after infra timeout; never measured): CSR counting-sort
// build (~260us: hist+scan+fill, scattered 4B stores) replaced by lock-free
// linked-list build (1 kernel, coalesced 8B stores):
//   k_build_chains: prev = atomicExch(head[dst[e]], e); nodes[e] = {prev, src[e]}
//   k_gather_chain_linear: wave per node, chase chain (wave-uniform), pipelined
//     so feat-row load overlaps next chain-node load; fused in-register
//     linear (readlane broadcast) + bias + relu.
// Fallback to atomic-scatter path if ws too small.

__device__ __forceinline__ float bcast_lane(float x, int k) {
    return __uint_as_float(__builtin_amdgcn_readlane(__float_as_uint(x), k));
}

// ---------------- chain build ----------------

__global__ void k_build_chains(const int* __restrict__ src,
                               const int* __restrict__ dst,
                               int* __restrict__ head,
                               int2* __restrict__ nodes, int E) {
    int e = blockIdx.x * blockDim.x + threadIdx.x;
    if (e < E) {
        int d = dst[e];
        int s = src[e];
        int prev = atomicExch(&head[d], e);   // random 4B RMW in 400KB (L2)
        nodes[e] = make_int2(prev, s);        // coalesced 8B store
    }
}

// ---------------- fused chain-gather + linear + relu ----------------
// wave per node (lane = feature). Chain pointers are wave-uniform; the loop is
// software-pipelined: while waiting on nodes[e] for step i+1, the feat row of
// step i is already in flight / being accumulated.

__global__ void k_gather_chain_linear(const float* __restrict__ feat,
                                      const float* __restrict__ W,
                                      const float* __restrict__ b,
                                      const int* __restrict__ head,
                                      const int2* __restrict__ nodes,
                                      float* __restrict__ out, int N) {
    int lane = threadIdx.x & 63;
    int wid = (blockIdx.x * blockDim.x + threadIdx.x) >> 6;
    int nw = (gridDim.x * blockDim.x) >> 6;

    // W row 'lane' (64 f32); compiler may cache in regs or re-load from L1.
    float4 w[16];
    const float4* Wv = (const float4*)(W + (lane << 6));
    #pragma unroll
    for (int q = 0; q < 16; ++q) w[q] = Wv[q];
    float bj = b[lane];

    for (int n = wid; n < N; n += nw) {
        float sum = 0.0f;
        int e = head[n];
        if (e >= 0) {
            int2 nd = nodes[e];
            float v = feat[(nd.y << 6) + lane];
            e = nd.x;
            while (e >= 0) {
                int2 nd2 = nodes[e];                  // serial chase (uniform)
                float v2 = feat[(nd2.y << 6) + lane]; // issue before consuming v
                sum += v;                             // v from previous step
                v = v2;
                e = nd2.x;
            }
            sum += v;
        }

        float acc = bj;
        #pragma unroll
        for (int k = 0; k < 64; ++k)
            acc = fmaf(bcast_lane(sum, k), ((const float*)w)[k], acc);
        out[(n << 6) + lane] = fmaxf(acc, 0.0f);
    }
}

// ---------------- fallback: atomic path ----------------

__global__ void gcn_scatter_kernel(const float* __restrict__ feat,
                                   const int* __restrict__ src,
                                   const int* __restrict__ dst,
                                   float* __restrict__ agg,
                                   int n_edges) {
    long long tid = (long long)blockIdx.x * blockDim.x + threadIdx.x;
    int e = (int)(tid >> 6);
    int f = (int)(tid & 63);
    if (e >= n_edges) return;
    atomicAdd(&agg[(long long)dst[e] * 64 + f], feat[(long long)src[e] * 64 + f]);
}

__global__ void gcn_linear_relu_kernel(const float* __restrict__ agg,
                                       const float* __restrict__ W,
                                       const float* __restrict__ b,
                                       float* __restrict__ out,
                                       int n_nodes) {
    __shared__ float Wt[64 * 65];
    __shared__ float bs[64];
    __shared__ float rows[4 * 64];
    int tid = threadIdx.x;
    #pragma unroll
    for (int it = 0; it < 16; ++it) {
        int idx = it * 256 + tid;
        Wt[(idx & 63) * 65 + (idx >> 6)] = W[idx];
    }
    if (tid < 64) bs[tid] = b[tid];
    __syncthreads();
    int li = tid >> 6, j = tid & 63;
    for (int r0 = blockIdx.x * 4; r0 < n_nodes; r0 += gridDim.x * 4) {
        int n = r0 + li;
        __syncthreads();
        if (n < n_nodes) rows[tid] = agg[(long long)n * 64 + j];
        __syncthreads();
        if (n < n_nodes) {
            float sum = bs[j];
            #pragma unroll
            for (int k = 0; k < 64; ++k)
                sum += rows[li * 64 + k] * Wt[k * 65 + j];
            out[(long long)n * 64 + j] = fmaxf(sum, 0.0f);
        }
    }
}

extern "C" void kernel_launch(void* const* d_in, const int* in_sizes, int n_in,
                              void* d_out, int out_size, void* d_ws, size_t ws_size,
                              hipStream_t stream) {
    const float* feat = (const float*)d_in[0];
    const float* W    = (const float*)d_in[1];
    const float* b    = (const float*)d_in[2];
    const int*   src  = (const int*)d_in[3];
    const int*   dst  = (const int*)d_in[4];
    float* out = (float*)d_out;

    int N = in_sizes[0] / 64;
    int E = in_sizes[3];

    // ws layout: head[N] (int) | nodes[E] (int2).  N*4 = 400000 (8B-divisible).
    size_t need = (size_t)N * sizeof(int) + (size_t)E * sizeof(int2);

    if (ws_size >= need) {
        int*  head  = (int*)d_ws;
        int2* nodes = (int2*)(head + N);

        hipMemsetAsync(head, 0xFF, (size_t)N * sizeof(int), stream);  // all -1

        k_build_chains<<<(E + 255) / 256, 256, 0, stream>>>(src, dst, head, nodes, E);

        k_gather_chain_linear<<<2048, 256, 0, stream>>>(feat, W, b, head, nodes, out, N);
    } else {
        // fallback: atomic scatter into out (in-place-safe linear)
        float* agg = out;
        hipMemsetAsync(agg, 0, (size_t)N * 64 * sizeof(float), stream);
        long long total = (long long)E * 64;
        gcn_scatter_kernel<<<(int)((total + 255) / 256), 256, 0, stream>>>(feat, src, dst, agg, E);
        gcn_linear_relu_kernel<<<1280, 256, 0, stream>>>(agg, W, b, out, N);
    }
}